// Round 7
// baseline (118.817 us; speedup 1.0000x reference)
//
#include <hip/hip_runtime.h>
#include <stdint.h>

#define C_DIM   256
#define L_ANCH  8
#define M_INST  64
#define NPIX    32768
#define LDSTR   264      // A-tile row stride (shorts)
#define WSTR    40       // prep W-tile row stride (shorts)
#define TSTR    80       // transpose tile row stride (shorts)

typedef __attribute__((ext_vector_type(8))) short  short8;   // 8 x bf16
typedef __attribute__((ext_vector_type(4))) float  float4v;  // MFMA C/D

__device__ __forceinline__ float bf2f(unsigned short b) {
    union { unsigned u; float f; } x; x.u = ((unsigned)b) << 16; return x.f;
}
__device__ __forceinline__ unsigned short f2bf(float f) {
    union { unsigned u; float f; } x; x.f = f;
    unsigned u = x.u;
    return (unsigned short)((u + 0x7FFFu + ((u >> 16) & 1u)) >> 16);  // RNE
}
__device__ __forceinline__ ushort4 f4bf(float4 f) {
    ushort4 v; v.x = f2bf(f.x); v.y = f2bf(f.y); v.z = f2bf(f.z); v.w = f2bf(f.w);
    return v;
}
// unpack 2 bf16 packed in a dword: 1 VALU op per element
__device__ __forceinline__ void bfx2(unsigned u, float& lo, float& hi) {
    union { unsigned u; float f; } a, b;
    a.u = u << 16; b.u = u & 0xffff0000u;
    lo = a.f; hi = b.f;
}

// ---------------------------------------------------------------------------
// P1: blocks 0..63    : K/V = anchors @ {Wk,Wv}^T + b via MFMA
//                       (b>>5 = mat, (b>>1)&15 = 32-row tile, b&1 = col half)
//     blocks 64..127  : convert out_w -> Owb (bf16)
//     blocks 128..143 : Wq -> WqT (bf16 TRANSPOSED) via LDS 64x64 tile
// (round-0 proven structure — prep restructures in r1-r4 all regressed)
// ---------------------------------------------------------------------------
__global__ __launch_bounds__(256) void prep1_kernel(
    const float* __restrict__ anchors, const float* __restrict__ in_proj_w,
    const float* __restrict__ in_proj_b, const float* __restrict__ out_w,
    unsigned short* __restrict__ Kb, unsigned short* __restrict__ Vb,
    unsigned short* __restrict__ WqT, unsigned short* __restrict__ Owb)
{
    __shared__ unsigned short Abuf[32 * LDSTR];
    __shared__ unsigned short Wtile[4][32 * WSTR];
    __shared__ unsigned short Ttile[64 * TSTR];
    const int b = blockIdx.x, t = threadIdx.x;

    if (b >= 128) {          // ---- WqT transpose: 16 blocks, 64x64 tiles ----
        const int tidx = b - 128;
        const int r0 = (tidx >> 2) * 64, c0 = (tidx & 3) * 64;
#pragma unroll
        for (int i = 0; i < 4; ++i) {
            int id = t + i * 256;            // 1024 float4 chunks
            int row = id >> 4, c4 = id & 15;
            float4 f = *(const float4*)&in_proj_w[(size_t)(r0 + row) * C_DIM + c0 + c4 * 4];
            Ttile[(c4 * 4 + 0) * TSTR + row] = f2bf(f.x);
            Ttile[(c4 * 4 + 1) * TSTR + row] = f2bf(f.y);
            Ttile[(c4 * 4 + 2) * TSTR + row] = f2bf(f.z);
            Ttile[(c4 * 4 + 3) * TSTR + row] = f2bf(f.w);
        }
        __syncthreads();
#pragma unroll
        for (int i = 0; i < 2; ++i) {
            int id = t + i * 256;            // 512 short8 chunks
            int cc = id >> 3, ch = id & 7;
            *(short8*)&WqT[(size_t)(c0 + cc) * C_DIM + r0 + ch * 8] =
                *(const short8*)&Ttile[cc * TSTR + ch * 8];
        }
        return;
    }

    if (b >= 64) {           // ---- Owb convert: 64 blocks ----
        const int id = (b - 64) * 256 + t;   // 16384 float4 chunks
        float4 f = *((const float4*)out_w + id);
        *((ushort4*)Owb + id) = f4bf(f);
        return;
    }

    // ---- K/V MFMA GEMM: 64 blocks (mat x 16 tiles x 2 col-halves) ----
    const int mat = b >> 5, tile = (b >> 1) & 15, half = b & 1;
    const int m0 = tile * 32;
#pragma unroll
    for (int i = 0; i < 8; ++i) {
        int id = t + i * 256;
        int row = id >> 6, c4 = id & 63;
        float4 f = *((const float4*)(anchors + (size_t)(m0 + row) * C_DIM) + c4);
        *(ushort4*)&Abuf[row * LDSTR + c4 * 4] = f4bf(f);
    }
    __syncthreads();

    const int wave = t >> 6, lane = t & 63, r16 = lane & 15, quad = lane >> 4;
    const int colbase = half * 128 + wave * 32;                 // 32 cols per wave
    const int wbase = C_DIM + mat * C_DIM + colbase;            // W row range
    unsigned short* Wl = &Wtile[wave][0];                       // 32 x WSTR

    float4v acc[2][2];
#pragma unroll
    for (int mt = 0; mt < 2; ++mt)
#pragma unroll
        for (int nt = 0; nt < 2; ++nt)
#pragma unroll
            for (int r = 0; r < 4; ++r) acc[mt][nt][r] = 0.f;

    for (int ks = 0; ks < 8; ++ks) {
        const int rr = lane >> 3, cc = lane & 7;
#pragma unroll
        for (int i = 0; i < 4; ++i) {
            int row = rr + i * 8;           // 32 W rows
            float4 f = *((const float4*)(in_proj_w + (size_t)(wbase + row) * C_DIM + ks * 32) + cc);
            *(ushort4*)&Wl[row * WSTR + cc * 4] = f4bf(f);
        }
        const int c0 = ks * 32 + quad * 8;
        short8 afr[2], bfr[2];
#pragma unroll
        for (int mt = 0; mt < 2; ++mt)
            afr[mt] = *(const short8*)&Abuf[(mt * 16 + r16) * LDSTR + c0];
#pragma unroll
        for (int nt = 0; nt < 2; ++nt)
            bfr[nt] = *(const short8*)&Wl[(nt * 16 + r16) * WSTR + quad * 8];
#pragma unroll
        for (int mt = 0; mt < 2; ++mt)
#pragma unroll
            for (int nt = 0; nt < 2; ++nt)
                acc[mt][nt] = __builtin_amdgcn_mfma_f32_16x16x32_bf16(
                    afr[mt], bfr[nt], acc[mt][nt], 0, 0, 0);
    }

    unsigned short* dst = mat ? Vb : Kb;
#pragma unroll
    for (int nt = 0; nt < 2; ++nt) {
        const int col = colbase + nt * 16 + r16;
        const float bias = in_proj_b[C_DIM + mat * C_DIM + col];
#pragma unroll
        for (int mt = 0; mt < 2; ++mt)
#pragma unroll
            for (int r = 0; r < 4; ++r) {
                int row = m0 + mt * 16 + quad * 4 + r;
                dst[(size_t)row * C_DIM + col] = f2bf(acc[mt][nt][r] + bias);
            }
    }
}

// ---------------------------------------------------------------------------
// P2: blocks 0..31 : G = K @ WqT^T + (g0 = K.bq on half==0)
//     blocks 32..63: U = V @ Owb^T
//   (b>>1)&15 = 32-row tile, b&1 = col half; round-0 proven pattern
// ---------------------------------------------------------------------------
__global__ __launch_bounds__(256) void prep2_kernel(
    const unsigned short* __restrict__ Kb, const unsigned short* __restrict__ Vb,
    const unsigned short* __restrict__ WqT, const unsigned short* __restrict__ Owb,
    const float* __restrict__ in_proj_b,
    unsigned short* __restrict__ G, unsigned short* __restrict__ U,
    float* __restrict__ g0)
{
    __shared__ unsigned short Abuf[32 * LDSTR];
    const int b = blockIdx.x, t = threadIdx.x;
    const int isG = (b < 32) ? 1 : 0;
    const int tile = (b >> 1) & 15, half = b & 1;
    const int m0 = tile * 32;
    const unsigned short* src = isG ? Kb : Vb;
    const unsigned short* W   = isG ? WqT : Owb;
    unsigned short* dst       = isG ? G : U;

#pragma unroll
    for (int i = 0; i < 4; ++i) {
        int id = t + i * 256;            // 1024 short8 chunks
        int row = id >> 5, c8 = id & 31;
        *(short8*)&Abuf[row * LDSTR + c8 * 8] =
            *(const short8*)&src[(size_t)(m0 + row) * C_DIM + c8 * 8];
    }
    __syncthreads();

    const int wave = t >> 6, lane = t & 63, r16 = lane & 15, quad = lane >> 4;

    if (isG && half == 0) {
        const int grow = t >> 3, gs = t & 7;
        float gp = 0.f;
#pragma unroll
        for (int c = 0; c < 32; ++c)
            gp += bf2f(Abuf[grow * LDSTR + gs * 32 + c]) * in_proj_b[gs * 32 + c];
        gp += __shfl_down(gp, 1);
        gp += __shfl_down(gp, 2);
        gp += __shfl_down(gp, 4);
        if (gs == 0) g0[m0 + grow] = gp;
    }

    const int colbase = half * 128 + wave * 32;

    float4v acc[2][2];
#pragma unroll
    for (int mt = 0; mt < 2; ++mt)
#pragma unroll
        for (int nt = 0; nt < 2; ++nt)
#pragma unroll
            for (int r = 0; r < 4; ++r) acc[mt][nt][r] = 0.f;

    for (int ks = 0; ks < 8; ++ks) {
        const int c0 = ks * 32 + quad * 8;
        short8 afr[2], bfr[2];
#pragma unroll
        for (int mt = 0; mt < 2; ++mt)
            afr[mt] = *(const short8*)&Abuf[(mt * 16 + r16) * LDSTR + c0];
#pragma unroll
        for (int nt = 0; nt < 2; ++nt)
            bfr[nt] = *(const short8*)&W[(size_t)(colbase + nt * 16 + r16) * C_DIM + c0];
#pragma unroll
        for (int mt = 0; mt < 2; ++mt)
#pragma unroll
            for (int nt = 0; nt < 2; ++nt)
                acc[mt][nt] = __builtin_amdgcn_mfma_f32_16x16x32_bf16(
                    afr[mt], bfr[nt], acc[mt][nt], 0, 0, 0);
    }

#pragma unroll
    for (int nt = 0; nt < 2; ++nt) {
        const int col = colbase + nt * 16 + r16;
#pragma unroll
        for (int mt = 0; mt < 2; ++mt)
#pragma unroll
            for (int r = 0; r < 4; ++r) {
                int row = m0 + mt * 16 + quad * 4 + r;
                dst[(size_t)row * C_DIM + col] = f2bf(acc[mt][nt][r]);
            }
    }
}

// ---------------------------------------------------------------------------
// gather: out = f + mask * (softmax((G[m].f + g0)/16) @ U[m] + out_b)
//   NEW: ONE WAVE PER PIXEL (64 lanes, 4 channels/lane), 4 pixels/block,
//   8192 blocks. vs round-6 (32 lanes/pixel):
//   - per-lane state halves again (fr[4]/y[4], est ~40-48 VGPR)
//   - m/lab are wave-uniform -> readfirstlane pins them to SGPR: G/U base
//     addrs + g0 loads become scalar, mask branch is wave-uniform
//   - dependent chain before the reduce halves (4-elem dot)
//   Cost: 6-stage butterfly (48 shuffles vs 40) — ds-pipe, cheap.
// ---------------------------------------------------------------------------
__global__ __launch_bounds__(256) void gather_kernel(
    const float* __restrict__ features, const int* __restrict__ inst,
    const float* __restrict__ out_b,
    const unsigned short* __restrict__ G, const unsigned short* __restrict__ U,
    const float* __restrict__ g0, float* __restrict__ out)
{
    const int t = threadIdx.x;
    const int p = t >> 6, s = t & 63;          // one wave per pixel
    const int n = blockIdx.x * 4 + p;
    const int lab = __builtin_amdgcn_readfirstlane(inst[n]);   // wave-uniform
    const int m = max(lab - 1, 0);
    const unsigned short* Gp = G + (size_t)m * (L_ANCH * C_DIM) + s * 4;
    const unsigned short* Up = U + (size_t)m * (L_ANCH * C_DIM) + s * 4;

    // f slice: 4 fp32 (channels s*4 .. s*4+4)
    float fr[4];
    *(float4*)fr = *(const float4*)(features + (size_t)n * C_DIM + s * 4);

    float4* op = (float4*)(out + (size_t)n * C_DIM + s * 4);

    if (lab == 0) {                            // wave-uniform passthrough
        float4 o; o.x = fr[0]; o.y = fr[1]; o.z = fr[2]; o.w = fr[3];
        *op = o;
        return;
    }

    float sc[L_ANCH];
#pragma unroll
    for (int l = 0; l < L_ANCH; ++l) {
        uint2 w = *(const uint2*)(Gp + (size_t)l * C_DIM);   // 4 bf16 of G row
        float lo, hi, a;
        bfx2(w.x, lo, hi); a  = lo * fr[0] + hi * fr[1];
        bfx2(w.y, lo, hi); a += lo * fr[2] + hi * fr[3];
        sc[l] = a;
    }

    const float4 g0a = *(const float4*)&g0[m * L_ANCH];      // SGPR loads (m uniform)
    const float4 g0b = *(const float4*)&g0[m * L_ANCH + 4];
    const float gb[L_ANCH] = {g0a.x, g0a.y, g0a.z, g0a.w, g0b.x, g0b.y, g0b.z, g0b.w};

    // butterfly reduce across the full wave; all lanes get the row sums
    float mx = -1e30f;
#pragma unroll
    for (int l = 0; l < L_ANCH; ++l) {
        float v = sc[l];
        v += __shfl_xor(v, 1);
        v += __shfl_xor(v, 2);
        v += __shfl_xor(v, 4);
        v += __shfl_xor(v, 8);
        v += __shfl_xor(v, 16);
        v += __shfl_xor(v, 32);
        v = (v + gb[l]) * 0.0625f;             // 1/sqrt(256)
        sc[l] = v;
        mx = fmaxf(mx, v);
    }
    float sum = 0.f;
#pragma unroll
    for (int l = 0; l < L_ANCH; ++l) { sc[l] = __expf(sc[l] - mx); sum += sc[l]; }
    const float inv = 1.f / sum;

    float y[4];
#pragma unroll
    for (int c = 0; c < 4; ++c) y[c] = 0.f;
#pragma unroll
    for (int l = 0; l < L_ANCH; ++l) {
        const float av = sc[l] * inv;
        uint2 u = *(const uint2*)(Up + (size_t)l * C_DIM);   // 4 bf16 of U row
        float lo, hi;
        bfx2(u.x, lo, hi); y[0] += av * lo; y[1] += av * hi;
        bfx2(u.y, lo, hi); y[2] += av * lo; y[3] += av * hi;
    }

    const float4 ob = *(const float4*)(out_b + s * 4);
    float4 o;
    o.x = fr[0] + y[0] + ob.x;
    o.y = fr[1] + y[1] + ob.y;
    o.z = fr[2] + y[2] + ob.z;
    o.w = fr[3] + y[3] + ob.w;
    *op = o;
}

// ---------------------------------------------------------------------------
extern "C" void kernel_launch(void* const* d_in, const int* in_sizes, int n_in,
                              void* d_out, int out_size, void* d_ws, size_t ws_size,
                              hipStream_t stream) {
    const float* anchors   = (const float*)d_in[0];
    const float* features  = (const float*)d_in[1];
    const int*   inst      = (const int*)d_in[2];
    const float* in_proj_w = (const float*)d_in[3];
    const float* in_proj_b = (const float*)d_in[4];
    const float* out_w     = (const float*)d_in[5];
    const float* out_b     = (const float*)d_in[6];
    float* out = (float*)d_out;

    unsigned short* Kb  = (unsigned short*)d_ws;              // 512*256 bf16
    unsigned short* Vb  = Kb  + M_INST * L_ANCH * C_DIM;      // 512*256
    unsigned short* WqT = Vb  + M_INST * L_ANCH * C_DIM;      // 256*256 (transposed)
    unsigned short* Owb = WqT + C_DIM * C_DIM;                // 256*256
    unsigned short* G   = Owb + C_DIM * C_DIM;                // 512*256
    unsigned short* U   = G   + M_INST * L_ANCH * C_DIM;      // 512*256
    float*          g0  = (float*)(U + M_INST * L_ANCH * C_DIM); // 512 fp32

    prep1_kernel<<<144, 256, 0, stream>>>(anchors, in_proj_w, in_proj_b, out_w,
                                          Kb, Vb, WqT, Owb);
    prep2_kernel<<<64, 256, 0, stream>>>(Kb, Vb, WqT, Owb, in_proj_b, G, U, g0);
    gather_kernel<<<NPIX / 4, 256, 0, stream>>>(features, inst, out_b, G, U, g0, out);
}

// Round 9
// 116.150 us; speedup vs baseline: 1.0230x; 1.0230x over previous
//
#include <hip/hip_runtime.h>
#include <stdint.h>

#define C_DIM   256
#define L_ANCH  8
#define M_INST  64
#define NPIX    32768
#define LDSTR   264      // A-tile row stride (shorts)
#define WSTR    40       // prep W-tile row stride (shorts)
#define TSTR    80       // transpose tile row stride (shorts)

typedef __attribute__((ext_vector_type(8))) short  short8;   // 8 x bf16
typedef __attribute__((ext_vector_type(4))) float  float4v;  // MFMA C/D + native vec

__device__ __forceinline__ float bf2f(unsigned short b) {
    union { unsigned u; float f; } x; x.u = ((unsigned)b) << 16; return x.f;
}
__device__ __forceinline__ unsigned short f2bf(float f) {
    union { unsigned u; float f; } x; x.f = f;
    unsigned u = x.u;
    return (unsigned short)((u + 0x7FFFu + ((u >> 16) & 1u)) >> 16);  // RNE
}
__device__ __forceinline__ ushort4 f4bf(float4 f) {
    ushort4 v; v.x = f2bf(f.x); v.y = f2bf(f.y); v.z = f2bf(f.z); v.w = f2bf(f.w);
    return v;
}
// unpack 2 bf16 packed in a dword: 1 VALU op per element
__device__ __forceinline__ void bfx2(unsigned u, float& lo, float& hi) {
    union { unsigned u; float f; } a, b;
    a.u = u << 16; b.u = u & 0xffff0000u;
    lo = a.f; hi = b.f;
}

// ---------------------------------------------------------------------------
// P1: blocks 0..63    : K/V = anchors @ {Wk,Wv}^T + b via MFMA
//                       (b>>5 = mat, (b>>1)&15 = 32-row tile, b&1 = col half)
//     blocks 64..127  : convert out_w -> Owb (bf16)
//     blocks 128..143 : Wq -> WqT (bf16 TRANSPOSED) via LDS 64x64 tile
// (round-0 proven structure — prep restructures in r1-r4 all regressed)
// ---------------------------------------------------------------------------
__global__ __launch_bounds__(256) void prep1_kernel(
    const float* __restrict__ anchors, const float* __restrict__ in_proj_w,
    const float* __restrict__ in_proj_b, const float* __restrict__ out_w,
    unsigned short* __restrict__ Kb, unsigned short* __restrict__ Vb,
    unsigned short* __restrict__ WqT, unsigned short* __restrict__ Owb)
{
    __shared__ unsigned short Abuf[32 * LDSTR];
    __shared__ unsigned short Wtile[4][32 * WSTR];
    __shared__ unsigned short Ttile[64 * TSTR];
    const int b = blockIdx.x, t = threadIdx.x;

    if (b >= 128) {          // ---- WqT transpose: 16 blocks, 64x64 tiles ----
        const int tidx = b - 128;
        const int r0 = (tidx >> 2) * 64, c0 = (tidx & 3) * 64;
#pragma unroll
        for (int i = 0; i < 4; ++i) {
            int id = t + i * 256;            // 1024 float4 chunks
            int row = id >> 4, c4 = id & 15;
            float4 f = *(const float4*)&in_proj_w[(size_t)(r0 + row) * C_DIM + c0 + c4 * 4];
            Ttile[(c4 * 4 + 0) * TSTR + row] = f2bf(f.x);
            Ttile[(c4 * 4 + 1) * TSTR + row] = f2bf(f.y);
            Ttile[(c4 * 4 + 2) * TSTR + row] = f2bf(f.z);
            Ttile[(c4 * 4 + 3) * TSTR + row] = f2bf(f.w);
        }
        __syncthreads();
#pragma unroll
        for (int i = 0; i < 2; ++i) {
            int id = t + i * 256;            // 512 short8 chunks
            int cc = id >> 3, ch = id & 7;
            *(short8*)&WqT[(size_t)(c0 + cc) * C_DIM + r0 + ch * 8] =
                *(const short8*)&Ttile[cc * TSTR + ch * 8];
        }
        return;
    }

    if (b >= 64) {           // ---- Owb convert: 64 blocks ----
        const int id = (b - 64) * 256 + t;   // 16384 float4 chunks
        float4 f = *((const float4*)out_w + id);
        *((ushort4*)Owb + id) = f4bf(f);
        return;
    }

    // ---- K/V MFMA GEMM: 64 blocks (mat x 16 tiles x 2 col-halves) ----
    const int mat = b >> 5, tile = (b >> 1) & 15, half = b & 1;
    const int m0 = tile * 32;
#pragma unroll
    for (int i = 0; i < 8; ++i) {
        int id = t + i * 256;
        int row = id >> 6, c4 = id & 63;
        float4 f = *((const float4*)(anchors + (size_t)(m0 + row) * C_DIM) + c4);
        *(ushort4*)&Abuf[row * LDSTR + c4 * 4] = f4bf(f);
    }
    __syncthreads();

    const int wave = t >> 6, lane = t & 63, r16 = lane & 15, quad = lane >> 4;
    const int colbase = half * 128 + wave * 32;                 // 32 cols per wave
    const int wbase = C_DIM + mat * C_DIM + colbase;            // W row range
    unsigned short* Wl = &Wtile[wave][0];                       // 32 x WSTR

    float4v acc[2][2];
#pragma unroll
    for (int mt = 0; mt < 2; ++mt)
#pragma unroll
        for (int nt = 0; nt < 2; ++nt)
#pragma unroll
            for (int r = 0; r < 4; ++r) acc[mt][nt][r] = 0.f;

    for (int ks = 0; ks < 8; ++ks) {
        const int rr = lane >> 3, cc = lane & 7;
#pragma unroll
        for (int i = 0; i < 4; ++i) {
            int row = rr + i * 8;           // 32 W rows
            float4 f = *((const float4*)(in_proj_w + (size_t)(wbase + row) * C_DIM + ks * 32) + cc);
            *(ushort4*)&Wl[row * WSTR + cc * 4] = f4bf(f);
        }
        const int c0 = ks * 32 + quad * 8;
        short8 afr[2], bfr[2];
#pragma unroll
        for (int mt = 0; mt < 2; ++mt)
            afr[mt] = *(const short8*)&Abuf[(mt * 16 + r16) * LDSTR + c0];
#pragma unroll
        for (int nt = 0; nt < 2; ++nt)
            bfr[nt] = *(const short8*)&Wl[(nt * 16 + r16) * WSTR + quad * 8];
#pragma unroll
        for (int mt = 0; mt < 2; ++mt)
#pragma unroll
            for (int nt = 0; nt < 2; ++nt)
                acc[mt][nt] = __builtin_amdgcn_mfma_f32_16x16x32_bf16(
                    afr[mt], bfr[nt], acc[mt][nt], 0, 0, 0);
    }

    unsigned short* dst = mat ? Vb : Kb;
#pragma unroll
    for (int nt = 0; nt < 2; ++nt) {
        const int col = colbase + nt * 16 + r16;
        const float bias = in_proj_b[C_DIM + mat * C_DIM + col];
#pragma unroll
        for (int mt = 0; mt < 2; ++mt)
#pragma unroll
            for (int r = 0; r < 4; ++r) {
                int row = m0 + mt * 16 + quad * 4 + r;
                dst[(size_t)row * C_DIM + col] = f2bf(acc[mt][nt][r] + bias);
            }
    }
}

// ---------------------------------------------------------------------------
// P2: blocks 0..31 : G = K @ WqT^T + (g0 = K.bq on half==0)
//     blocks 32..63: U = V @ Owb^T
//   (b>>1)&15 = 32-row tile, b&1 = col half; round-0 proven pattern
// ---------------------------------------------------------------------------
__global__ __launch_bounds__(256) void prep2_kernel(
    const unsigned short* __restrict__ Kb, const unsigned short* __restrict__ Vb,
    const unsigned short* __restrict__ WqT, const unsigned short* __restrict__ Owb,
    const float* __restrict__ in_proj_b,
    unsigned short* __restrict__ G, unsigned short* __restrict__ U,
    float* __restrict__ g0)
{
    __shared__ unsigned short Abuf[32 * LDSTR];
    const int b = blockIdx.x, t = threadIdx.x;
    const int isG = (b < 32) ? 1 : 0;
    const int tile = (b >> 1) & 15, half = b & 1;
    const int m0 = tile * 32;
    const unsigned short* src = isG ? Kb : Vb;
    const unsigned short* W   = isG ? WqT : Owb;
    unsigned short* dst       = isG ? G : U;

#pragma unroll
    for (int i = 0; i < 4; ++i) {
        int id = t + i * 256;            // 1024 short8 chunks
        int row = id >> 5, c8 = id & 31;
        *(short8*)&Abuf[row * LDSTR + c8 * 8] =
            *(const short8*)&src[(size_t)(m0 + row) * C_DIM + c8 * 8];
    }
    __syncthreads();

    const int wave = t >> 6, lane = t & 63, r16 = lane & 15, quad = lane >> 4;

    if (isG && half == 0) {
        const int grow = t >> 3, gs = t & 7;
        float gp = 0.f;
#pragma unroll
        for (int c = 0; c < 32; ++c)
            gp += bf2f(Abuf[grow * LDSTR + gs * 32 + c]) * in_proj_b[gs * 32 + c];
        gp += __shfl_down(gp, 1);
        gp += __shfl_down(gp, 2);
        gp += __shfl_down(gp, 4);
        if (gs == 0) g0[m0 + grow] = gp;
    }

    const int colbase = half * 128 + wave * 32;

    float4v acc[2][2];
#pragma unroll
    for (int mt = 0; mt < 2; ++mt)
#pragma unroll
        for (int nt = 0; nt < 2; ++nt)
#pragma unroll
            for (int r = 0; r < 4; ++r) acc[mt][nt][r] = 0.f;

    for (int ks = 0; ks < 8; ++ks) {
        const int c0 = ks * 32 + quad * 8;
        short8 afr[2], bfr[2];
#pragma unroll
        for (int mt = 0; mt < 2; ++mt)
            afr[mt] = *(const short8*)&Abuf[(mt * 16 + r16) * LDSTR + c0];
#pragma unroll
        for (int nt = 0; nt < 2; ++nt)
            bfr[nt] = *(const short8*)&W[(size_t)(colbase + nt * 16 + r16) * C_DIM + c0];
#pragma unroll
        for (int mt = 0; mt < 2; ++mt)
#pragma unroll
            for (int nt = 0; nt < 2; ++nt)
                acc[mt][nt] = __builtin_amdgcn_mfma_f32_16x16x32_bf16(
                    afr[mt], bfr[nt], acc[mt][nt], 0, 0, 0);
    }

#pragma unroll
    for (int nt = 0; nt < 2; ++nt) {
        const int col = colbase + nt * 16 + r16;
#pragma unroll
        for (int mt = 0; mt < 2; ++mt)
#pragma unroll
            for (int r = 0; r < 4; ++r) {
                int row = m0 + mt * 16 + quad * 4 + r;
                dst[(size_t)row * C_DIM + col] = f2bf(acc[mt][nt][r]);
            }
    }
}

// ---------------------------------------------------------------------------
// gather: out = f + mask * (softmax((G[m].f + g0)/16) @ U[m] + out_b)
//   32 lanes/pixel (8 channels/lane), 8 pixels/block, 4096 blocks — the
//   round-6 proven optimum of the lane-width family (16 lanes: too much
//   live state / short on waves; 64 lanes: uint2 loads + 6-stage butterfly
//   cost more than the chain savings).
//   Only change vs round 6: non-temporal output stores via native vector
//   type (out is write-once, never re-read; keeps the 33.5MB output stream
//   from evicting G/U in L2). NOTE: __builtin_nontemporal_store requires a
//   NATIVE vector type — HIP's float4 class doesn't compile (round-8 error).
// ---------------------------------------------------------------------------
__global__ __launch_bounds__(256) void gather_kernel(
    const float* __restrict__ features, const int* __restrict__ inst,
    const float* __restrict__ out_b,
    const unsigned short* __restrict__ G, const unsigned short* __restrict__ U,
    const float* __restrict__ g0, float* __restrict__ out)
{
    const int t = threadIdx.x;
    const int p = t >> 5, s = t & 31;          // 32 lanes per pixel
    const int n = blockIdx.x * 8 + p;
    const int lab = inst[n];
    const int m = max(lab - 1, 0);
    const unsigned short* Gp = G + (size_t)m * (L_ANCH * C_DIM) + s * 8;
    const unsigned short* Up = U + (size_t)m * (L_ANCH * C_DIM) + s * 8;

    // f slice: 8 fp32 (channels s*8 .. s*8+8)
    float fr[8];
    const float4* fp = (const float4*)(features + (size_t)n * C_DIM + s * 8);
    *(float4*)&fr[0] = fp[0];
    *(float4*)&fr[4] = fp[1];

    float sc[L_ANCH];
#pragma unroll
    for (int l = 0; l < L_ANCH; ++l) {
        uint4 w = *(const uint4*)(Gp + (size_t)l * C_DIM);   // 8 bf16 of G row
        float lo, hi, a;
        bfx2(w.x, lo, hi); a  = lo * fr[0] + hi * fr[1];
        bfx2(w.y, lo, hi); a += lo * fr[2] + hi * fr[3];
        bfx2(w.z, lo, hi); a += lo * fr[4] + hi * fr[5];
        bfx2(w.w, lo, hi); a += lo * fr[6] + hi * fr[7];
        sc[l] = a;
    }

    const float4 g0a = *(const float4*)&g0[m * L_ANCH];
    const float4 g0b = *(const float4*)&g0[m * L_ANCH + 4];
    const float gb[L_ANCH] = {g0a.x, g0a.y, g0a.z, g0a.w, g0b.x, g0b.y, g0b.z, g0b.w};

    // butterfly reduce within each 32-lane pixel group; all lanes get sums
    float mx = -1e30f;
#pragma unroll
    for (int l = 0; l < L_ANCH; ++l) {
        float v = sc[l];
        v += __shfl_xor(v, 1);
        v += __shfl_xor(v, 2);
        v += __shfl_xor(v, 4);
        v += __shfl_xor(v, 8);
        v += __shfl_xor(v, 16);
        v = (v + gb[l]) * 0.0625f;             // 1/sqrt(256)
        sc[l] = v;
        mx = fmaxf(mx, v);
    }
    float sum = 0.f;
#pragma unroll
    for (int l = 0; l < L_ANCH; ++l) { sc[l] = __expf(sc[l] - mx); sum += sc[l]; }
    const float inv = 1.f / sum;

    float y[8];
#pragma unroll
    for (int c = 0; c < 8; ++c) y[c] = 0.f;
#pragma unroll
    for (int l = 0; l < L_ANCH; ++l) {
        const float av = sc[l] * inv;
        uint4 u = *(const uint4*)(Up + (size_t)l * C_DIM);   // 8 bf16 of U row
        float lo, hi;
        bfx2(u.x, lo, hi); y[0] += av * lo; y[1] += av * hi;
        bfx2(u.y, lo, hi); y[2] += av * lo; y[3] += av * hi;
        bfx2(u.z, lo, hi); y[4] += av * lo; y[5] += av * hi;
        bfx2(u.w, lo, hi); y[6] += av * lo; y[7] += av * hi;
    }

    const float fm = (lab > 0) ? 1.f : 0.f;
    float4v* op = (float4v*)(out + (size_t)n * C_DIM + s * 8);
    const float4* obp = (const float4*)(out_b + s * 8);
#pragma unroll
    for (int i = 0; i < 2; ++i) {
        float4 ob = obp[i];
        float4v o;
        o[0] = fr[i * 4 + 0] + fm * (y[i * 4 + 0] + ob.x);
        o[1] = fr[i * 4 + 1] + fm * (y[i * 4 + 1] + ob.y);
        o[2] = fr[i * 4 + 2] + fm * (y[i * 4 + 2] + ob.z);
        o[3] = fr[i * 4 + 3] + fm * (y[i * 4 + 3] + ob.w);
        __builtin_nontemporal_store(o, op + i);
    }
}

// ---------------------------------------------------------------------------
extern "C" void kernel_launch(void* const* d_in, const int* in_sizes, int n_in,
                              void* d_out, int out_size, void* d_ws, size_t ws_size,
                              hipStream_t stream) {
    const float* anchors   = (const float*)d_in[0];
    const float* features  = (const float*)d_in[1];
    const int*   inst      = (const int*)d_in[2];
    const float* in_proj_w = (const float*)d_in[3];
    const float* in_proj_b = (const float*)d_in[4];
    const float* out_w     = (const float*)d_in[5];
    const float* out_b     = (const float*)d_in[6];
    float* out = (float*)d_out;

    unsigned short* Kb  = (unsigned short*)d_ws;              // 512*256 bf16
    unsigned short* Vb  = Kb  + M_INST * L_ANCH * C_DIM;      // 512*256
    unsigned short* WqT = Vb  + M_INST * L_ANCH * C_DIM;      // 256*256 (transposed)
    unsigned short* Owb = WqT + C_DIM * C_DIM;                // 256*256
    unsigned short* G   = Owb + C_DIM * C_DIM;                // 512*256
    unsigned short* U   = G   + M_INST * L_ANCH * C_DIM;      // 512*256
    float*          g0  = (float*)(U + M_INST * L_ANCH * C_DIM); // 512 fp32

    prep1_kernel<<<144, 256, 0, stream>>>(anchors, in_proj_w, in_proj_b, out_w,
                                          Kb, Vb, WqT, Owb);
    prep2_kernel<<<64, 256, 0, stream>>>(Kb, Vb, WqT, Owb, in_proj_b, G, U, g0);
    gather_kernel<<<NPIX / 8, 256, 0, stream>>>(features, inst, out_b, G, U, g0, out);
}